// Round 6
// baseline (3038.180 us; speedup 1.0000x reference)
//
#include <hip/hip_runtime.h>
#include <hip/hip_bf16.h>

#define HH 51
#define TPB 512     // 8 waves; wave w owns batch b=w in PA, 4 matmul jobs in PB
#define BPB 8
#define GMS 9       // gm row stride (floats): 9i mod 32 -> <=2-way banks

typedef _Float16 half8 __attribute__((ext_vector_type(8)));
typedef float f4 __attribute__((ext_vector_type(4)));

__device__ __forceinline__ float bf2f(unsigned short u) {
    return __uint_as_float(((unsigned)u) << 16);
}
__device__ __forceinline__ float loadf(const void* p, size_t i, bool bf) {
    return bf ? bf2f(((const unsigned short*)p)[i]) : ((const float*)p)[i];
}
__device__ __forceinline__ void storef(void* p, size_t i, float v, bool bf) {
    if (bf) ((__hip_bfloat16*)p)[i] = __float2bfloat16(v);
    else    ((float*)p)[i] = v;
}
__device__ __forceinline__ float sigm(float v) {
    float e = __expf(-fabsf(v));
    float s = 1.0f / (1.0f + e);
    return (v >= 0.0f) ? s : 1.0f - s;
}
__device__ __forceinline__ float tanh_fast(float v) {
    float e = __expf(-2.0f * fabsf(v));
    float t = (1.0f - e) / (1.0f + e);
    return (v >= 0.0f) ? t : -t;
}
__device__ __forceinline__ f4 MF(half8 a, half8 b, f4 c) {
    return __builtin_amdgcn_mfma_f32_16x16x32_f16(a, b, c, 0, 0, 0);
}
// wave64 sum via DPP (VALU pipe, no LDS): rocPRIM sequence, result uniform
__device__ __forceinline__ float wave_sum(float x) {
    float s = x, t;
    t = __builtin_bit_cast(float, __builtin_amdgcn_update_dpp(0, __builtin_bit_cast(int, s), 0x111, 0xf, 0xf, true)); s += t;
    t = __builtin_bit_cast(float, __builtin_amdgcn_update_dpp(0, __builtin_bit_cast(int, s), 0x112, 0xf, 0xf, true)); s += t;
    t = __builtin_bit_cast(float, __builtin_amdgcn_update_dpp(0, __builtin_bit_cast(int, s), 0x114, 0xf, 0xf, true)); s += t;
    t = __builtin_bit_cast(float, __builtin_amdgcn_update_dpp(0, __builtin_bit_cast(int, s), 0x118, 0xf, 0xf, true)); s += t;
    t = __builtin_bit_cast(float, __builtin_amdgcn_update_dpp(0, __builtin_bit_cast(int, s), 0x142, 0xa, 0xf, true)); s += t;
    t = __builtin_bit_cast(float, __builtin_amdgcn_update_dpp(0, __builtin_bit_cast(int, s), 0x143, 0xc, 0xf, true)); s += t;
    return __builtin_bit_cast(float, __builtin_amdgcn_readlane(__builtin_bit_cast(int, s), 63));
}

// LDS (35200 B). Staging [0,20480) halves[160][64] per matrix, 3 rounds (UNION).
// Runtime: gmA@0 gmB@5760 gmC@11520 (160*9*4=5760 each)
//          h1hi@17280 h1lo@19584 h2hi@21888 h2lo@24192 (16*72*2=2304 each)
//          xbuf@26496 [2][8][68] f32 | obuf@30848 [2][8][68] f32
__global__ __launch_bounds__(TPB, 2) void gru_kernel(
    const void* __restrict__ xg,
    const void* __restrict__ wih1, const void* __restrict__ whh1,
    const void* __restrict__ bih1, const void* __restrict__ bhh1,
    const void* __restrict__ wih2, const void* __restrict__ whh2,
    const void* __restrict__ bih2, const void* __restrict__ bhh2,
    const void* __restrict__ wlin, const void* __restrict__ blin_p,
    void* __restrict__ dout, int T, int TF)
{
    __shared__ __align__(16) char L[35200];
    float*    gmA  = (float*)L;
    float*    gmB  = (float*)(L + 5760);
    float*    gmC  = (float*)(L + 11520);
    _Float16* h1hi = (_Float16*)(L + 17280);
    _Float16* h1lo = (_Float16*)(L + 19584);
    _Float16* h2hi = (_Float16*)(L + 21888);
    _Float16* h2lo = (_Float16*)(L + 24192);
    float*    xbuf = (float*)(L + 26496);
    float*    obuf = (float*)(L + 30848);

    const int tid = threadIdx.x, w = tid >> 6, lane = tid & 63;
    const int n16 = lane & 15, quad = lane >> 4;
    const int b = w;                       // PA: batch per wave
    const int bg0 = blockIdx.x * BPB;
    const bool li = lane < HH;
    const int il = li ? lane : 0;

    // ---- runtime dtype detection (fp32 vs bf16), uniform ----
    bool isbf;
    {
        const unsigned short* u = (const unsigned short*)whh1;
        int ok = 1;
#pragma unroll
        for (int k = 0; k < 16; ++k) {
            unsigned e = (u[2 * k] >> 7) & 0xFF;
            ok &= (e >= 100 && e <= 125) ? 1 : 0;
        }
        isbf = (ok != 0);
    }

    // ---- per-wave matmul job table ----
    // w<3: gh2 tiles {w,w+3,w+6,w+9} (A=h2, dst=gmB); w>=3: jj=(w-3)+5q:
    //   jj<10 -> gh1 tile jj (dst gmA); else gi2 tile jj-10 (dst gmC). A=h1.
    int jtl[4], jmat[4], njobs;
    float* jdst[4];
#pragma unroll
    for (int q = 0; q < 4; ++q) { jtl[q] = 0; jmat[q] = 1; jdst[q] = gmB; }
    if (w < 3) {
        njobs = (w == 0) ? 4 : 3;
#pragma unroll
        for (int q = 0; q < 4; ++q) {
            int tl = w + 3 * q;
            jtl[q] = (tl < 10) ? tl : 0; jmat[q] = 1; jdst[q] = gmB;
        }
    } else {
        njobs = 4;
#pragma unroll
        for (int q = 0; q < 4; ++q) {
            int jj = (w - 3) + 5 * q;
            if (jj < 10) { jtl[q] = jj; jmat[q] = 0; jdst[q] = gmA; }
            else         { jtl[q] = jj - 10; jmat[q] = 2; jdst[q] = gmC; }
        }
    }
    const _Float16* ahi = (w < 3) ? h2hi : h1hi;
    const _Float16* alo = (w < 3) ? h2lo : h1lo;

    // ---- staging rounds: one matrix at a time, snapshot frags ----
    half8 FW[4][2];
    _Float16* stg = (_Float16*)L;
    for (int mt = 0; mt < 3; ++mt) {
        const void* wm = (mt == 0) ? whh1 : (mt == 1) ? whh2 : wih2;
        for (int e = tid; e < 160 * 64; e += TPB) {
            int g = e >> 6, k = e & 63;
            float v = 0.0f;
            if (g < 3 * HH) {
                if (k < HH) v = loadf(wm, (size_t)g * HH + k, isbf);
                else if (k == 52) {
                    if (mt == 0)      v = loadf(bhh1, g, isbf) + ((g < 2 * HH) ? loadf(bih1, g, isbf) : 0.0f);
                    else if (mt == 1) v = loadf(bhh2, g, isbf);
                    else              v = loadf(bih2, g, isbf);
                }
            }
            stg[e] = (_Float16)v;
        }
        __syncthreads();
#pragma unroll
        for (int q = 0; q < 4; ++q)
            if (q < njobs && jmat[q] == mt) {
                FW[q][0] = *(const half8*)(stg + (size_t)(16 * jtl[q] + n16) * 64 + quad * 8);
                FW[q][1] = *(const half8*)(stg + (size_t)(16 * jtl[q] + n16) * 64 + 32 + quad * 8);
            }
        __syncthreads();
    }

    // ---- runtime buffer init ----
    for (int e = tid; e < 2304; e += TPB) ((unsigned*)(L + 17280))[e] = 0u;  // h bufs
    {   // x chunk 0
        int bb = tid >> 6, tt = tid & 63;
        xbuf[bb * 68 + tt] = (tt < T) ? loadf(xg, (size_t)(bg0 + bb) * T + tt, isbf) : 0.0f;
    }
    float wr1 = 0, wz1 = 0, wn1 = 0, bn1 = 0, wl = 0;
    if (li) {
        wr1 = loadf(wih1, il, isbf);          wz1 = loadf(wih1, HH + il, isbf);
        wn1 = loadf(wih1, 2 * HH + il, isbf); bn1 = loadf(bih1, 2 * HH + il, isbf);
        wl  = loadf(wlin, il, isbf);
    }
    const float blv = loadf(blin_p, 0, isbf);
    __syncthreads();
    if (tid < BPB) { h1hi[tid * 72 + 52] = (_Float16)1.0f; h2hi[tid * 72 + 52] = (_Float16)1.0f; }
    __syncthreads();

    // ---- prologue: gmA = gh1(0) (bias-only h1) ----
    {
        half8 A0 = *(const half8*)(ahi + n16 * 72 + quad * 8);
        half8 A1 = *(const half8*)(ahi + n16 * 72 + 32 + quad * 8);
        half8 A2 = *(const half8*)(alo + n16 * 72 + quad * 8);
        half8 A3 = *(const half8*)(alo + n16 * 72 + 32 + quad * 8);
#pragma unroll
        for (int q = 0; q < 4; ++q)
            if (q < njobs && jmat[q] == 0) {
                f4 acc = {0.f, 0.f, 0.f, 0.f};
                acc = MF(A0, FW[q][0], acc); acc = MF(A1, FW[q][1], acc);
                acc = MF(A2, FW[q][0], acc); acc = MF(A3, FW[q][1], acc);
                if (quad < 2) {
                    float* d = jdst[q] + (16 * jtl[q] + n16) * GMS + 4 * quad;
                    d[0] = acc[0]; d[1] = acc[1]; d[2] = acc[2]; d[3] = acc[3];
                }
            }
    }
    __syncthreads();

    float h1p = 0.0f, h2p = 0.0f;

    for (int t = 0; t < TF; ++t) {
        const int c = t >> 6, sl = t & 63;

        // ======== PA: elementwise, one batch per wave ========
        float p = 0.0f;
        if (t > 0) {       // e2(t-1)
            float gir = gmC[il * GMS + b], giz = gmC[(HH + il) * GMS + b], gin = gmC[(2 * HH + il) * GMS + b];
            float ghr = gmB[il * GMS + b], ghz = gmB[(HH + il) * GMS + b], ghn = gmB[(2 * HH + il) * GMS + b];
            float r2 = sigm(gir + ghr);
            float z2 = sigm(giz + ghz);
            float n2 = tanh_fast(gin + r2 * ghn);
            float h = n2 + z2 * (h2p - n2); h2p = h;
            if (li) {
                _Float16 hi = (_Float16)h;
                h2hi[b * 72 + il] = hi;
                h2lo[b * 72 + il] = (_Float16)(h - (float)hi);
                p = h * wl;
            }
        }
        float outv = wave_sum(p) + blv;                  // out(t-1), wave-uniform
        if (t > 0 && lane == 0)
            obuf[(((t - 1) >> 6) & 1) * 544 + b * 68 + ((t - 1) & 63)] = outv;
        {                  // e1(t)
            float xv = (t < T) ? xbuf[(c & 1) * 544 + b * 68 + sl] : outv;
            float ar = gmA[il * GMS + b], az = gmA[(HH + il) * GMS + b], an = gmA[(2 * HH + il) * GMS + b];
            float r = sigm(fmaf(xv, wr1, ar));
            float z = sigm(fmaf(xv, wz1, az));
            float n = tanh_fast(fmaf(xv, wn1, bn1) + r * an);
            float h = n + z * (h1p - n); h1p = h;
            if (li) {
                _Float16 hi = (_Float16)h;
                h1hi[b * 72 + il] = hi;
                h1lo[b * 72 + il] = (_Float16)(h - (float)hi);
            }
        }
        __syncthreads();

        // ======== PB: 30 tile-matmuls over all 8 waves + amortized I/O ========
        if (sl == 0) {
            int bb = tid >> 6, tt = tid & 63;
            if (t > 0)
                storef(dout, (size_t)(bg0 + bb) * TF + (t - 64) + tt,
                       obuf[((c - 1) & 1) * 544 + bb * 68 + tt], isbf);
            int cn = c + 1, src = cn * 64 + tt;
            if (cn * 64 < T)
                xbuf[(cn & 1) * 544 + bb * 68 + tt] =
                    (src < T) ? loadf(xg, (size_t)(bg0 + bb) * T + src, isbf) : 0.0f;
        }
        {
            half8 A0 = *(const half8*)(ahi + n16 * 72 + quad * 8);
            half8 A1 = *(const half8*)(ahi + n16 * 72 + 32 + quad * 8);
            half8 A2 = *(const half8*)(alo + n16 * 72 + quad * 8);
            half8 A3 = *(const half8*)(alo + n16 * 72 + 32 + quad * 8);
#pragma unroll
            for (int q = 0; q < 4; ++q)
                if (q < njobs) {
                    f4 acc = {0.f, 0.f, 0.f, 0.f};
                    acc = MF(A0, FW[q][0], acc); acc = MF(A1, FW[q][1], acc);
                    acc = MF(A2, FW[q][0], acc); acc = MF(A3, FW[q][1], acc);
                    if (quad < 2) {
                        float* d = jdst[q] + (16 * jtl[q] + n16) * GMS + 4 * quad;
                        d[0] = acc[0]; d[1] = acc[1]; d[2] = acc[2]; d[3] = acc[3];
                    }
                }
        }
        __syncthreads();
    }

    // ---- final e2(TF-1) ----
    {
        float p = 0.0f;
        {
            float gir = gmC[il * GMS + b], giz = gmC[(HH + il) * GMS + b], gin = gmC[(2 * HH + il) * GMS + b];
            float ghr = gmB[il * GMS + b], ghz = gmB[(HH + il) * GMS + b], ghn = gmB[(2 * HH + il) * GMS + b];
            float r2 = sigm(gir + ghr);
            float z2 = sigm(giz + ghz);
            float n2 = tanh_fast(gin + r2 * ghn);
            float h = n2 + z2 * (h2p - n2);
            if (li) p = h * wl;
        }
        float outv = wave_sum(p) + blv;
        if (lane == 0)
            obuf[(((TF - 1) >> 6) & 1) * 544 + b * 68 + ((TF - 1) & 63)] = outv;
    }
    __syncthreads();
    {
        int lastF = (TF - 1) & ~63, rem = TF - lastF;
        for (int e = tid; e < BPB * rem; e += TPB) {
            int bb = e / rem, tt = e % rem;
            storef(dout, (size_t)(bg0 + bb) * TF + lastF + tt,
                   obuf[((lastF >> 6) & 1) * 544 + bb * 68 + tt], isbf);
        }
    }
}

extern "C" void kernel_launch(void* const* d_in, const int* in_sizes, int n_in,
                              void* d_out, int out_size, void* d_ws, size_t ws_size,
                              hipStream_t stream) {
    const int B = 2048;
    const int T = in_sizes[0] / B;   // 1000
    const int TF = out_size / B;     // 2000
    gru_kernel<<<dim3(B / BPB), dim3(TPB), 0, stream>>>(
        d_in[0], d_in[1], d_in[2], d_in[3], d_in[4], d_in[5],
        d_in[6], d_in[7], d_in[8], d_in[9], d_in[10],
        d_out, T, TF);
}